// Round 13
// baseline (2395.107 us; speedup 1.0000x reference)
//
#include <hip/hip_runtime.h>
#include <hip/hip_bf16.h>
#include <type_traits>

typedef __bf16 bf16;
typedef __attribute__((ext_vector_type(8))) __bf16 bf16x8;
typedef __attribute__((ext_vector_type(4))) __bf16 bf16x4;
typedef __attribute__((ext_vector_type(4))) float f32x4;

#define TOKENS 15360   // B*S = 16*960
#define HID    512
#define FFN_D  2048
#define QKV_D  1536

// ---------------------------------------------------------------------------
// fast exact-GELU: A&S 7.1.26 erf (|eps|<=1.5e-7), hw exp + hw rcp
// ---------------------------------------------------------------------------
__device__ __forceinline__ float gelu_erf(float x) {
  const float z = fabsf(x) * 0.70710678118654752f;
#if __has_builtin(__builtin_amdgcn_rcpf)
  const float t = __builtin_amdgcn_rcpf(fmaf(0.3275911f, z, 1.f));
#else
  const float t = 1.f / fmaf(0.3275911f, z, 1.f);
#endif
  float p = fmaf(1.061405429f, t, -1.453152027f);
  p = fmaf(p, t, 1.421413741f);
  p = fmaf(p, t, -0.284496736f);
  p = fmaf(p, t, 0.254829592f);
  p *= t;
  const float e  = __expf(-z * z);
  const float er = fmaf(-p, e, 1.f);          // erf(|x|/sqrt2)
  return 0.5f * x * (1.f + copysignf(er, x));
}

// ---------------------------------------------------------------------------
// fp32 -> bf16 weight conversion (run every launch; ws is re-poisoned)
// ---------------------------------------------------------------------------
__global__ __launch_bounds__(256) void cvt_kernel(const float* __restrict__ src,
                                                  bf16* __restrict__ dst, int n4) {
  const int i = (blockIdx.x * 256 + threadIdx.x);
  if (i >= n4) return;
  const float4 v = ((const float4*)src)[i];
  bf16x4 d = {(bf16)v.x, (bf16)v.y, (bf16)v.z, (bf16)v.w};
  *(bf16x4*)(dst + (size_t)i * 4) = d;
}

// ---------------------------------------------------------------------------
// GEMM: C[M,N] = A[M,K] @ W[N,K]^T (+bias fp32, + optional residual / GELU).
// Round 11 structure (best measured): 128x128 tile, BK=64, 4 waves, each
// 64x64 via 4x4 mfma_f32_16x16x32_bf16. Double-buffered LDS (2 blocks/CU;
// cross-block overlap fills the per-K-tile stall). K-loop unrolled by 2 so
// the LDS buffer index is COMPILE-TIME (r11 verified VALUBusy 44->34%).
// 2-phase pipeline:
//   stage(next); s_waitcnt vmcnt(8); s_barrier; compute(cur); s_barrier
// Counted vmcnt(8) = next tile's 8 loads stay in flight; in-order VMEM
// retirement => current tile landed. Only the last K-tile drains vmcnt(0).
// nt = K/64 is ALWAYS EVEN (8, 16 or 32) -> clean unroll-by-2.
// grid = (N/128, M/128), XCD-chunked n-fastest ordering (FETCH = A-once).
// XOR swizzle (slot c holds k-chunk c^(r&7)): async-copy contiguity + 2-way
// (free) ds_read_b128.
// Round 13: LDS-TRANSPOSE EPILOGUE. After the K-loop (As/Bs dead), acc+bias
// (+gelu) is written as f32 into Cs (stride 132: phase-1 bank (16qd+4r+li)%32
// = 2-way free; 528-B row stride keeps f32x4 16B-aligned), then each thread
// handles one half-row: coalesced f32x4 LDS reads + bf16x8 residual load +
// 8x16B coalesced stores (was: 32 scattered 2B stores + 32 scalar R loads).
// Residual numerics unchanged (f32 add, single rounding). In-place out==R
// safe (single touch per element, read-then-write within thread).
// LDS 67584 B <= 80 KB keeps 2 blocks/CU.
// ---------------------------------------------------------------------------
#define EPI_BIAS_BF16     0   // out = v
#define EPI_BIAS_RES_BF16 1   // out = v + R
#define EPI_BIAS_GELU     2   // out = gelu(v)

template <int EPI>
__global__ __launch_bounds__(256) void gemm_bt(
    const bf16* __restrict__ A, const bf16* __restrict__ W,
    const float* __restrict__ bias, const bf16* __restrict__ R,
    bf16* __restrict__ out, int M, int N, int K) {
  __shared__ __align__(16) char smem[132 * 128 * 4];   // 67584 B union
  bf16* As = (bf16*)smem;                // 2*128*64 bf16 = 32 KB
  bf16* Bs = (bf16*)(smem + 32768);      // 32 KB

  const int tid  = threadIdx.x;
  const int lane = tid & 63;
  const int wv   = tid >> 6;
  const int li   = lane & 15;
  const int qd   = lane >> 4;
  const int mw   = (wv & 1) << 6;
  const int nw   = (wv >> 1) << 6;

  // XCD-chunked, n-fastest logical ordering. grid = (NB = N/128, MB = M/128).
  const int NB  = gridDim.x;
  const int nwg = NB * gridDim.y;
  int lid = blockIdx.y * NB + blockIdx.x;
  if ((nwg & 7) == 0) lid = (lid & 7) * (nwg >> 3) + (lid >> 3);
  const int n0 = (lid % NB) << 7;
  const int m0 = (lid / NB) << 7;

  f32x4 acc[4][4];
#pragma unroll
  for (int i = 0; i < 4; ++i)
#pragma unroll
    for (int j = 0; j < 4; ++j) acc[i][j] = (f32x4){0.f, 0.f, 0.f, 0.f};

  // staging addresses: tid-invariant parts hoisted; pointers advance by BK
  const bf16* pa[4];
  const bf16* pb[4];
  int off[4];
#pragma unroll
  for (int it = 0; it < 4; ++it) {
    const int fc   = it * 256 + tid;
    const int r    = fc >> 3;
    const int c    = fc & 7;
    const int koff = (c ^ (r & 7)) << 3;
    pa[it]  = A + (size_t)(m0 + r) * K + koff;
    pb[it]  = W + (size_t)(n0 + r) * K + koff;
    off[it] = (it * 256 + (tid & 192)) * 8;  // wave-uniform LDS base (elems)
  }

  auto stage = [&](int buf) {   // 8 global_load_lds per thread (4 A + 4 B)
#pragma unroll
    for (int it = 0; it < 4; ++it) {
      __builtin_amdgcn_global_load_lds(
          (const __attribute__((address_space(1))) unsigned int*)pa[it],
          (__attribute__((address_space(3))) unsigned int*)(As + buf * 8192 + off[it]),
          16, 0, 0);
      pa[it] += 64;
    }
#pragma unroll
    for (int it = 0; it < 4; ++it) {
      __builtin_amdgcn_global_load_lds(
          (const __attribute__((address_space(1))) unsigned int*)pb[it],
          (__attribute__((address_space(3))) unsigned int*)(Bs + buf * 8192 + off[it]),
          16, 0, 0);
      pb[it] += 64;
    }
  };

  // BUF is a compile-time constant -> ds_read addresses are loop-invariant
  // (hoisted) with immediate LDS offsets.
  auto compute = [&](auto bufc) {
    constexpr int buf = decltype(bufc)::value;
    const bf16* Ab = As + buf * 8192;
    const bf16* Bb = Bs + buf * 8192;
#pragma unroll
    for (int ks = 0; ks < 2; ++ks) {
      const int ck = (ks << 2) + qd;         // A/B frag: k-chunk = quad (+4*ks)
      bf16x8 af[4], bfv[4];
#pragma unroll
      for (int i = 0; i < 4; ++i) {
        const int mr = mw + i * 16 + li;     // mr&7 == li&7
        af[i] = *(const bf16x8*)(Ab + mr * 64 + ((ck ^ (li & 7)) << 3));
      }
#pragma unroll
      for (int j = 0; j < 4; ++j) {
        const int nr = nw + j * 16 + li;
        bfv[j] = *(const bf16x8*)(Bb + nr * 64 + ((ck ^ (li & 7)) << 3));
      }
#pragma unroll
      for (int i = 0; i < 4; ++i)
#pragma unroll
        for (int j = 0; j < 4; ++j)
          acc[i][j] = __builtin_amdgcn_mfma_f32_16x16x32_bf16(af[i], bfv[j],
                                                              acc[i][j], 0, 0, 0);
    }
  };

  const int nt = K >> 6;   // 8, 16 or 32: always even, >= 2
  stage(0);                // tile 0 -> buf 0
  for (int t = 0; t < nt - 2; t += 2) {
    stage(1);              // tile t+1 -> buf 1
    asm volatile("s_waitcnt vmcnt(8)" ::: "memory");  // tile t landed
    __builtin_amdgcn_s_barrier();
    asm volatile("" ::: "memory");
    compute(std::integral_constant<int, 0>{});
    asm volatile("" ::: "memory");
    __builtin_amdgcn_s_barrier();
    asm volatile("" ::: "memory");
    stage(0);              // tile t+2 -> buf 0
    asm volatile("s_waitcnt vmcnt(8)" ::: "memory");  // tile t+1 landed
    __builtin_amdgcn_s_barrier();
    asm volatile("" ::: "memory");
    compute(std::integral_constant<int, 1>{});
    asm volatile("" ::: "memory");
    __builtin_amdgcn_s_barrier();
    asm volatile("" ::: "memory");
  }
  // tail pair: tiles nt-2 (buf0, already staged) and nt-1 (buf1)
  stage(1);
  asm volatile("s_waitcnt vmcnt(8)" ::: "memory");    // tile nt-2 landed
  __builtin_amdgcn_s_barrier();
  asm volatile("" ::: "memory");
  compute(std::integral_constant<int, 0>{});
  asm volatile("" ::: "memory");
  __builtin_amdgcn_s_barrier();
  asm volatile("" ::: "memory");
  asm volatile("s_waitcnt vmcnt(0)" ::: "memory");    // tile nt-1 landed
  __builtin_amdgcn_s_barrier();
  asm volatile("" ::: "memory");
  compute(std::integral_constant<int, 1>{});

  // ---- epilogue phase 1: acc (+bias, +gelu) -> Cs f32 (stride 132) ----
  // barrier: all waves' final ds_reads retired (data-dep waits precede their
  // MFMAs, which precede this barrier in program order) => safe to overwrite.
  asm volatile("" ::: "memory");
  __builtin_amdgcn_s_barrier();
  asm volatile("" ::: "memory");
  float* Cs = (float*)smem;
#pragma unroll
  for (int j = 0; j < 4; ++j) {
    const int ncol = nw + j * 16 + li;
    const float bv = bias[n0 + ncol];
#pragma unroll
    for (int i = 0; i < 4; ++i) {
#pragma unroll
      for (int r = 0; r < 4; ++r) {
        float v = acc[i][j][r] + bv;
        if (EPI == EPI_BIAS_GELU) v = gelu_erf(v);
        Cs[(mw + i * 16 + qd * 4 + r) * 132 + ncol] = v;
      }
    }
  }
  asm volatile("" ::: "memory");
  __builtin_amdgcn_s_barrier();
  asm volatile("" ::: "memory");

  // ---- phase 2: coalesced LDS read + vector residual + bf16x8 stores ----
  {
    const int row  = tid >> 1;       // 0..127
    const int half = tid & 1;        // 64-col half
    const float* crow = Cs + row * 132 + half * 64;
    const size_t goff = (size_t)(m0 + row) * N + n0 + half * 64;
    bf16* orow = out + goff;
    const bf16* rrow = R + goff;     // only read when EPI_BIAS_RES_BF16
#pragma unroll
    for (int u = 0; u < 8; ++u) {
      const f32x4 a = *(const f32x4*)(crow + u * 8);
      const f32x4 c = *(const f32x4*)(crow + u * 8 + 4);
      float v[8] = {a[0], a[1], a[2], a[3], c[0], c[1], c[2], c[3]};
      if (EPI == EPI_BIAS_RES_BF16) {
        const bf16x8 rv = *(const bf16x8*)(rrow + u * 8);
#pragma unroll
        for (int k2 = 0; k2 < 8; ++k2) v[k2] += (float)rv[k2];
      }
      bf16x8 o;
#pragma unroll
      for (int k2 = 0; k2 < 8; ++k2) o[k2] = (bf16)v[k2];
      *(bf16x8*)(orow + u * 8) = o;
    }
  }
}

// ---------------------------------------------------------------------------
// MFMA attention: one block (4 waves) per (sequence, head).
// P padded to PP (16-mult) for tiles; K-dim of PV padded to PK (32-mult).
// Softmax is group-parallel (G lanes per row, shfl_xor reduce).
// ---------------------------------------------------------------------------
template <int P>
__global__ __launch_bounds__(256) void attn_kernel(const bf16* __restrict__ qkv,
                                                   bf16* __restrict__ out) {
  constexpr int PP   = ((P + 15) / 16) * 16;   // 32, 48, 96
  constexpr int PK   = ((PP + 31) / 32) * 32;  // 32, 64, 96
  constexpr int MT   = PP / 16;
  constexpr int SSTR = PP + 2;                 // fp32 words
  constexpr int VSTR = PK + 8;                 // bf16 elems; *2B is 16B-mult
  constexpr int PSTR = PK + 8;
  constexpr int G    = (P * 8 <= 256) ? 8 : ((P * 4 <= 256) ? 4 : 2);

  __shared__ __align__(16) bf16 QK[2 * PP * 64];  // Q | K ; reused as Ps
  __shared__ __align__(16) bf16 Vt[64 * VSTR];
  __shared__ __align__(16) float Sm[PP * SSTR];
  __shared__ float rsum[PP];

  bf16* Qs = QK;
  bf16* Ks = QK + PP * 64;
  bf16* Ps = QK;  // overlays Q/K after S phase (dead by then)

  const int tid  = threadIdx.x;
  const int lane = tid & 63;
  const int wv   = tid >> 6;
  const int li   = lane & 15;
  const int qd   = lane >> 4;
  const int n    = blockIdx.x >> 3;
  const int h    = blockIdx.x & 7;
  const bf16* base = qkv + (size_t)n * P * QKV_D + h * 64;

  // stage Q,K: 16B chunks, slot = c ^ (r&7)
  for (int t = tid; t < P * 8; t += 256) {
    const int r = t >> 3, c = t & 7;
    const bf16x8 qv = *(const bf16x8*)(base + (size_t)r * QKV_D + c * 8);
    const bf16x8 kv = *(const bf16x8*)(base + (size_t)r * QKV_D + 512 + c * 8);
    *(bf16x8*)(Qs + r * 64 + ((c ^ (r & 7)) * 8)) = qv;
    *(bf16x8*)(Ks + r * 64 + ((c ^ (r & 7)) * 8)) = kv;
  }
  // stage V^T
  for (int t = tid; t < P * 8; t += 256) {
    const int j = t % P, dc = t / P;
    const bf16x8 vv = *(const bf16x8*)(base + (size_t)j * QKV_D + 1024 + dc * 8);
#pragma unroll
    for (int u = 0; u < 8; ++u) Vt[(dc * 8 + u) * VSTR + j] = vv[u];
  }
  if constexpr (PK > P) {
    for (int t = tid; t < 64 * (PK - P); t += 256) {
      const int d = t / (PK - P), j = P + t % (PK - P);
      Vt[d * VSTR + j] = (bf16)0.f;
    }
  }
  __syncthreads();

  // S = Q K^T
  for (int t = wv; t < MT * MT; t += 4) {
    const int ti = t / MT, tj = t % MT;
    f32x4 acc = (f32x4){0.f, 0.f, 0.f, 0.f};
#pragma unroll
    for (int ks = 0; ks < 2; ++ks) {
      const int ck = ks * 4 + qd;
      const int ar = ti * 16 + li;
      const int br = tj * 16 + li;
      const bf16x8 af = *(const bf16x8*)(Qs + ar * 64 + ((ck ^ (ar & 7)) * 8));
      const bf16x8 bv = *(const bf16x8*)(Ks + br * 64 + ((ck ^ (br & 7)) * 8));
      acc = __builtin_amdgcn_mfma_f32_16x16x32_bf16(af, bv, acc, 0, 0, 0);
    }
#pragma unroll
    for (int r = 0; r < 4; ++r)
      Sm[(ti * 16 + qd * 4 + r) * SSTR + tj * 16 + li] = acc[r];
  }
  __syncthreads();

  // softmax: G lanes per row (G|64, groups lane-aligned so shfl_xor stays
  // in-group). unnormalized exp -> bf16 Ps; 1/sum saved for O-write.
  if (tid < P * G) {
    const int row = tid / G, g = tid % G;
    const float* srow = Sm + row * SSTR;
    bf16* prow = Ps + row * PSTR;
    float mx = -1e30f;
    for (int j = g; j < P; j += G) mx = fmaxf(mx, srow[j]);
#pragma unroll
    for (int m = G >> 1; m; m >>= 1) mx = fmaxf(mx, __shfl_xor(mx, m, 64));
    mx *= 0.125f;  // 1/sqrt(64)
    float sum = 0.f;
    for (int j = g; j < P; j += G) {
      const float e = __expf(srow[j] * 0.125f - mx);
      sum += e;
      prow[j] = (bf16)e;
    }
#pragma unroll
    for (int m = G >> 1; m; m >>= 1) sum += __shfl_xor(sum, m, 64);
    for (int j = P + g; j < PK; j += G) prow[j] = (bf16)0.f;
    if (g == 0) rsum[row] = 1.f / sum;
  }
  __syncthreads();

  // O = P V
  for (int t = wv; t < MT * 4; t += 4) {
    const int ti = t >> 2, td = t & 3;
    f32x4 acc = (f32x4){0.f, 0.f, 0.f, 0.f};
#pragma unroll
    for (int ks = 0; ks < PK / 32; ++ks) {
      const int ck = ks * 4 + qd;
      const bf16x8 af = *(const bf16x8*)(Ps + (ti * 16 + li) * PSTR + ck * 8);
      const bf16x8 bv = *(const bf16x8*)(Vt + (td * 16 + li) * VSTR + ck * 8);
      acc = __builtin_amdgcn_mfma_f32_16x16x32_bf16(af, bv, acc, 0, 0, 0);
    }
#pragma unroll
    for (int r = 0; r < 4; ++r) {
      const int row = ti * 16 + qd * 4 + r;
      if (row < P)
        out[(size_t)(n * P + row) * HID + h * 64 + td * 16 + li] =
            (bf16)(acc[r] * rsum[row]);
    }
  }
}

// ---------------------------------------------------------------------------
// LayerNorm over 512, one wave per row. bf16x8 loads/stores. In-place safe
// (each thread reads its own 8 elems, then writes the same 8).
// ---------------------------------------------------------------------------
__global__ __launch_bounds__(256) void ln_kernel(const bf16* __restrict__ Y,
                                                 const float* __restrict__ w,
                                                 const float* __restrict__ b,
                                                 bf16* __restrict__ X) {
  const int row  = blockIdx.x * 4 + (threadIdx.x >> 6);
  const int lane = threadIdx.x & 63;
  const bf16x8 yv = *(const bf16x8*)(Y + (size_t)row * HID + 8 * lane);
  float y[8];
#pragma unroll
  for (int u = 0; u < 8; ++u) y[u] = (float)yv[u];
  float s = 0.f, s2 = 0.f;
#pragma unroll
  for (int u = 0; u < 8; ++u) { s += y[u]; s2 += y[u] * y[u]; }
#pragma unroll
  for (int off = 32; off > 0; off >>= 1) {
    s  += __shfl_xor(s, off, 64);
    s2 += __shfl_xor(s2, off, 64);
  }
  const float mean = s * (1.f / 512.f);
  const float var  = s2 * (1.f / 512.f) - mean * mean;
  const float rstd = rsqrtf(var + 1e-5f);
  const float4 w0 = ((const float4*)w)[2 * lane];
  const float4 w1 = ((const float4*)w)[2 * lane + 1];
  const float4 b0 = ((const float4*)b)[2 * lane];
  const float4 b1 = ((const float4*)b)[2 * lane + 1];
  const float wr[8] = {w0.x, w0.y, w0.z, w0.w, w1.x, w1.y, w1.z, w1.w};
  const float br[8] = {b0.x, b0.y, b0.z, b0.w, b1.x, b1.y, b1.z, b1.w};
  bf16x8 o;
#pragma unroll
  for (int u = 0; u < 8; ++u) o[u] = (bf16)((y[u] - mean) * rstd * wr[u] + br[u]);
  *(bf16x8*)(X + (size_t)row * HID + 8 * lane) = o;
}

// ---------------------------------------------------------------------------
// input projection: h[r,o] = sum_k x[r,k]*w[o,k] + b[o], K=7. Writes the same
// value to nbr consecutive [TOKENS,HID] slices (branches share the input).
// ---------------------------------------------------------------------------
__global__ __launch_bounds__(256) void inproj_kernel(const float* __restrict__ x,
                                                     const float* __restrict__ w,
                                                     const float* __restrict__ b,
                                                     bf16* __restrict__ h,
                                                     int nbr) {
  const int idx = blockIdx.x * 256 + threadIdx.x;
  const int r = idx >> 9, o = idx & 511;
  float s = b[o];
#pragma unroll
  for (int k = 0; k < 7; ++k) s += x[r * 7 + k] * w[o * 7 + k];
  const bf16 bv = (bf16)s;
  for (int q = 0; q < nbr; ++q) h[idx + (size_t)q * TOKENS * HID] = bv;
}

// acc[row] (+)= X[row,:] . w  (per-branch final projection accumulate)
__global__ __launch_bounds__(256) void outdot_kernel(const bf16* __restrict__ X,
                                                     const float* __restrict__ w,
                                                     float* __restrict__ acc,
                                                     int first) {
  const int row  = blockIdx.x * 4 + (threadIdx.x >> 6);
  const int lane = threadIdx.x & 63;
  const bf16* xr = X + (size_t)row * HID;
  const bf16x8 xa = *(const bf16x8*)(xr + 8 * lane);
  const float4 wa = ((const float4*)w)[2 * lane];
  const float4 wb = ((const float4*)w)[2 * lane + 1];
  float s = (float)xa[0] * wa.x + (float)xa[1] * wa.y + (float)xa[2] * wa.z +
            (float)xa[3] * wa.w + (float)xa[4] * wb.x + (float)xa[5] * wb.y +
            (float)xa[6] * wb.z + (float)xa[7] * wb.w;
#pragma unroll
  for (int off = 32; off > 0; off >>= 1) s += __shfl_xor(s, off, 64);
  if (lane == 0) acc[row] = first ? s : (acc[row] + s);
}

// out[b,o] = (1/30) * sum_{j<10} acc[b*960 + o*10 + j] + b_out   (fp32 out)
__global__ __launch_bounds__(256) void pool_kernel(const float* __restrict__ acc,
                                                   const float* __restrict__ ob,
                                                   float* __restrict__ out) {
  const int idx = blockIdx.x * 256 + threadIdx.x;
  if (idx >= 16 * 96) return;
  const int bb = idx / 96, o = idx % 96;
  float s = 0.f;
#pragma unroll
  for (int j = 0; j < 10; ++j) s += acc[bb * 960 + o * 10 + j];
  out[idx] = s * (1.f / 30.f) + ob[0];
}

// ---------------------------------------------------------------------------
extern "C" void kernel_launch(void* const* d_in, const int* in_sizes, int n_in,
                              void* d_out, int out_size, void* d_ws,
                              size_t ws_size, hipStream_t stream) {
  const float* x          = (const float*)d_in[0];
  const float* ip_w       = (const float*)d_in[1];
  const float* ip_b       = (const float*)d_in[2];
  const float* in_proj_w  = (const float*)d_in[3];
  const float* in_proj_b  = (const float*)d_in[4];
  const float* out_proj_w = (const float*)d_in[5];
  const float* out_proj_b = (const float*)d_in[6];
  const float* ffn_w1     = (const float*)d_in[7];
  const float* ffn_b1     = (const float*)d_in[8];
  const float* ffn_w2     = (const float*)d_in[9];
  const float* ffn_b2     = (const float*)d_in[10];
  const float* ln1_w      = (const float*)d_in[11];
  const float* ln1_b      = (const float*)d_in[12];
  const float* ln2_w      = (const float*)d_in[13];
  const float* ln2_b      = (const float*)d_in[14];
  const float* op_w       = (const float*)d_in[15];
  const float* op_b       = (const float*)d_in[16];

  // fixed carve: weights + ACC, then activations (path-dependent)
  char* p = (char*)d_ws;
  bf16* Wq = (bf16*)p; p += (size_t)4 * QKV_D * HID * 2;
  bf16* Wo = (bf16*)p; p += (size_t)4 * HID * HID * 2;
  bf16* W1 = (bf16*)p; p += (size_t)4 * FFN_D * HID * 2;
  bf16* W2 = (bf16*)p; p += (size_t)4 * HID * FFN_D * 2;  // natural layout
  float* ACC = (float*)p; p += (size_t)TOKENS * 4;
  const size_t remain = ws_size - (size_t)(p - (char*)d_ws);

  const size_t T3 = 3 * (size_t)TOKENS;
  // pre-LN buffer eliminated (residual GEMMs write X IN PLACE; LN in place):
  //  batched: X bf16 [T3,512] + BUF bf16 [T3,2048]  ~236 MB
  //           attn phase: QKV [0,1536) | ATT [1536,2048) in BUF
  //           ffn  phase: H = all of BUF (QKV+ATT dead)
  //  seq:     X + BUF over TOKENS rows  ~79 MB
  const size_t need_batched = T3 * HID * 2 + T3 * (size_t)FFN_D * 2;
  const size_t need_seq     = (size_t)TOKENS * HID * 2 + (size_t)TOKENS * FFN_D * 2;
  const bool batched = remain >= need_batched;
  if (!batched && remain < need_seq) return;

  {  // weight conversion fp32 -> bf16 (all natural layouts)
    const int nq = 4 * QKV_D * HID / 4, no = 4 * HID * HID / 4,
              n1 = 4 * FFN_D * HID / 4, n2 = 4 * HID * FFN_D / 4;
    cvt_kernel<<<(nq + 255) / 256, 256, 0, stream>>>(in_proj_w, Wq, nq);
    cvt_kernel<<<(no + 255) / 256, 256, 0, stream>>>(out_proj_w, Wo, no);
    cvt_kernel<<<(n1 + 255) / 256, 256, 0, stream>>>(ffn_w1, W1, n1);
    cvt_kernel<<<(n2 + 255) / 256, 256, 0, stream>>>(ffn_w2, W2, n2);
  }

  static const int periods[3] = {24, 48, 96};
  auto launch_attn = [&](int P, const bf16* q, bf16* o) {
    const int nblk = (TOKENS / P) * 8;
    if (P == 24)      attn_kernel<24><<<nblk, 256, 0, stream>>>(q, o);
    else if (P == 48) attn_kernel<48><<<nblk, 256, 0, stream>>>(q, o);
    else              attn_kernel<96><<<nblk, 256, 0, stream>>>(q, o);
  };

  // one transformer layer on M rows. X updated IN PLACE through the residual
  // chain (see r12 liveness argument). qkvM: layer-0 batched computes QKV
  // once over TOKENS rows (branches share X).
  auto run_layer = [&](int l, int M, int qkvM, bf16* X, bf16* QKV, bf16* ATT,
                       bf16* H, bool all_br, int br) {
    const int MB = M / 128;
    gemm_bt<EPI_BIAS_BF16><<<dim3(QKV_D / 128, qkvM / 128), 256, 0, stream>>>(
        X, Wq + (size_t)l * QKV_D * HID, in_proj_b + l * QKV_D, nullptr,
        QKV, qkvM, QKV_D, HID);
    if (all_br) {
      for (int b2 = 0; b2 < 3; ++b2) {
        const bf16* q = QKV + (qkvM == M ? (size_t)b2 * TOKENS * QKV_D : 0);
        launch_attn(periods[b2], q, ATT + (size_t)b2 * TOKENS * HID);
      }
    } else {
      launch_attn(periods[br], QKV, ATT);
    }
    gemm_bt<EPI_BIAS_RES_BF16><<<dim3(HID / 128, MB), 256, 0, stream>>>(
        ATT, Wo + (size_t)l * HID * HID, out_proj_b + l * HID, X, X,
        M, HID, HID);
    ln_kernel<<<M / 4, 256, 0, stream>>>(X, ln1_w + l * HID, ln1_b + l * HID, X);
    gemm_bt<EPI_BIAS_GELU><<<dim3(FFN_D / 128, MB), 256, 0, stream>>>(
        X, W1 + (size_t)l * FFN_D * HID, ffn_b1 + l * FFN_D, nullptr,
        H, M, FFN_D, HID);
    gemm_bt<EPI_BIAS_RES_BF16><<<dim3(HID / 128, MB), 256, 0, stream>>>(
        H, W2 + (size_t)l * HID * FFN_D, ffn_b2 + l * HID, X, X,
        M, HID, FFN_D);
    ln_kernel<<<M / 4, 256, 0, stream>>>(X, ln2_w + l * HID, ln2_b + l * HID, X);
  };

  if (batched) {
    bf16* X   = (bf16*)p; p += T3 * HID * 2;
    bf16* BUF = (bf16*)p;
    bf16* QKV = BUF;
    bf16* ATT = BUF + T3 * QKV_D;
    bf16* H   = BUF;               // full T3 x 2048 (QKV+ATT dead by then)
    const int M = (int)T3;

    inproj_kernel<<<TOKENS * HID / 256, 256, 0, stream>>>(x, ip_w, ip_b, X, 3);
    for (int l = 0; l < 4; ++l)
      run_layer(l, M, l == 0 ? TOKENS : M, X, QKV, ATT, H, true, 0);
    for (int br = 0; br < 3; ++br)
      outdot_kernel<<<TOKENS / 4, 256, 0, stream>>>(
          X + (size_t)br * TOKENS * HID, op_w, ACC, br == 0);
  } else {
    // sequential (fits in ~79 MB)
    bf16* X   = (bf16*)p; p += (size_t)TOKENS * HID * 2;
    bf16* BUF = (bf16*)p;
    bf16* QKV = BUF;
    bf16* ATT = BUF + (size_t)TOKENS * QKV_D;
    bf16* H   = BUF;
    const int M = TOKENS;

    for (int br = 0; br < 3; ++br) {
      inproj_kernel<<<TOKENS * HID / 256, 256, 0, stream>>>(x, ip_w, ip_b, X, 1);
      for (int l = 0; l < 4; ++l)
        run_layer(l, M, M, X, QKV, ATT, H, false, br);
      outdot_kernel<<<TOKENS / 4, 256, 0, stream>>>(X, op_w, ACC, br == 0);
    }
  }
  pool_kernel<<<6, 256, 0, stream>>>(ACC, op_b, (float*)d_out);
}

// Round 14
// 1883.880 us; speedup vs baseline: 1.2714x; 1.2714x over previous
//
#include <hip/hip_runtime.h>
#include <hip/hip_bf16.h>
#include <type_traits>

typedef __bf16 bf16;
typedef __attribute__((ext_vector_type(8))) __bf16 bf16x8;
typedef __attribute__((ext_vector_type(4))) __bf16 bf16x4;
typedef __attribute__((ext_vector_type(4))) float f32x4;

#define TOKENS 15360   // B*S = 16*960
#define HID    512
#define FFN_D  2048
#define QKV_D  1536

// ---------------------------------------------------------------------------
// fast exact-GELU: A&S 7.1.26 erf (|eps|<=1.5e-7), hw exp + hw rcp
// ---------------------------------------------------------------------------
__device__ __forceinline__ float gelu_erf(float x) {
  const float z = fabsf(x) * 0.70710678118654752f;
#if __has_builtin(__builtin_amdgcn_rcpf)
  const float t = __builtin_amdgcn_rcpf(fmaf(0.3275911f, z, 1.f));
#else
  const float t = 1.f / fmaf(0.3275911f, z, 1.f);
#endif
  float p = fmaf(1.061405429f, t, -1.453152027f);
  p = fmaf(p, t, 1.421413741f);
  p = fmaf(p, t, -0.284496736f);
  p = fmaf(p, t, 0.254829592f);
  p *= t;
  const float e  = __expf(-z * z);
  const float er = fmaf(-p, e, 1.f);          // erf(|x|/sqrt2)
  return 0.5f * x * (1.f + copysignf(er, x));
}

// ---------------------------------------------------------------------------
// fp32 -> bf16 weight conversion (run every launch; ws is re-poisoned)
// ---------------------------------------------------------------------------
__global__ __launch_bounds__(256) void cvt_kernel(const float* __restrict__ src,
                                                  bf16* __restrict__ dst, int n4) {
  const int i = (blockIdx.x * 256 + threadIdx.x);
  if (i >= n4) return;
  const float4 v = ((const float4*)src)[i];
  bf16x4 d = {(bf16)v.x, (bf16)v.y, (bf16)v.z, (bf16)v.w};
  *(bf16x4*)(dst + (size_t)i * 4) = d;
}

// ---------------------------------------------------------------------------
// GEMM: C[M,N] = A[M,K] @ W[N,K]^T (+bias fp32, + optional residual / GELU).
// Round 11 structure (best measured): 128x128 tile, BK=64, 4 waves, each
// 64x64 via 4x4 mfma_f32_16x16x32_bf16. Double-buffered LDS (64 KB -> 2
// blocks/CU; cross-block overlap fills the per-K-tile stall). K-loop
// unrolled by 2 so the LDS buffer index is COMPILE-TIME (ds_read addresses
// loop-invariant: base VGPR + imm offset; r11 verified VALUBusy 44->34%,
// QKV 103->91 us). 2-phase pipeline:
//   stage(next); s_waitcnt vmcnt(8); s_barrier; compute(cur); s_barrier
// Counted vmcnt(8) = next tile's 8 loads stay in flight; in-order VMEM
// retirement => current tile landed. Only the last K-tile drains vmcnt(0).
// nt = K/64 is ALWAYS EVEN here (8, 16 or 32) -> clean unroll-by-2.
// grid = (N/128, M/128), XCD-chunked n-fastest ordering (FETCH = A-once,
// round-5 verified). XOR swizzle (slot c holds k-chunk c^(r&7)) keeps
// async-copy contiguity AND makes ds_read_b128 2-way (free, measured 0).
// Direct scattered epilogue (r13's LDS-transpose epilogue REVERTED: its
// phase-2 ds_read_b128 pattern was an 8-way bank conflict, 1.47M/dispatch,
// +26% dur). All epilogues write bf16; residual read bf16; ONE TOUCH per
// element => in-place out==R is safe (pre-LN buffer eliminated: residual
// GEMMs write X in place; old X value dead at its single residual read).
// ---------------------------------------------------------------------------
#define EPI_BIAS_BF16     0   // out = v
#define EPI_BIAS_RES_BF16 1   // out = v + R
#define EPI_BIAS_GELU     2   // out = gelu(v)

template <int EPI>
__global__ __launch_bounds__(256) void gemm_bt(
    const bf16* __restrict__ A, const bf16* __restrict__ W,
    const float* __restrict__ bias, const bf16* __restrict__ R,
    bf16* __restrict__ out, int M, int N, int K) {
  __shared__ __align__(16) bf16 As[2 * 128 * 64];
  __shared__ __align__(16) bf16 Bs[2 * 128 * 64];

  const int tid  = threadIdx.x;
  const int lane = tid & 63;
  const int wv   = tid >> 6;
  const int li   = lane & 15;
  const int qd   = lane >> 4;
  const int mw   = (wv & 1) << 6;
  const int nw   = (wv >> 1) << 6;

  // XCD-chunked, n-fastest logical ordering. grid = (NB = N/128, MB = M/128).
  const int NB  = gridDim.x;
  const int nwg = NB * gridDim.y;
  int lid = blockIdx.y * NB + blockIdx.x;
  if ((nwg & 7) == 0) lid = (lid & 7) * (nwg >> 3) + (lid >> 3);
  const int n0 = (lid % NB) << 7;
  const int m0 = (lid / NB) << 7;

  f32x4 acc[4][4];
#pragma unroll
  for (int i = 0; i < 4; ++i)
#pragma unroll
    for (int j = 0; j < 4; ++j) acc[i][j] = (f32x4){0.f, 0.f, 0.f, 0.f};

  // staging addresses: tid-invariant parts hoisted; pointers advance by BK
  const bf16* pa[4];
  const bf16* pb[4];
  int off[4];
#pragma unroll
  for (int it = 0; it < 4; ++it) {
    const int fc   = it * 256 + tid;
    const int r    = fc >> 3;
    const int c    = fc & 7;
    const int koff = (c ^ (r & 7)) << 3;
    pa[it]  = A + (size_t)(m0 + r) * K + koff;
    pb[it]  = W + (size_t)(n0 + r) * K + koff;
    off[it] = (it * 256 + (tid & 192)) * 8;  // wave-uniform LDS base (elems)
  }

  auto stage = [&](int buf) {   // 8 global_load_lds per thread (4 A + 4 B)
#pragma unroll
    for (int it = 0; it < 4; ++it) {
      __builtin_amdgcn_global_load_lds(
          (const __attribute__((address_space(1))) unsigned int*)pa[it],
          (__attribute__((address_space(3))) unsigned int*)(As + buf * 8192 + off[it]),
          16, 0, 0);
      pa[it] += 64;
    }
#pragma unroll
    for (int it = 0; it < 4; ++it) {
      __builtin_amdgcn_global_load_lds(
          (const __attribute__((address_space(1))) unsigned int*)pb[it],
          (__attribute__((address_space(3))) unsigned int*)(Bs + buf * 8192 + off[it]),
          16, 0, 0);
      pb[it] += 64;
    }
  };

  // BUF is a compile-time constant -> ds_read addresses are loop-invariant
  // (hoisted) with immediate LDS offsets.
  auto compute = [&](auto bufc) {
    constexpr int buf = decltype(bufc)::value;
    const bf16* Ab = As + buf * 8192;
    const bf16* Bb = Bs + buf * 8192;
#pragma unroll
    for (int ks = 0; ks < 2; ++ks) {
      const int ck = (ks << 2) + qd;         // A/B frag: k-chunk = quad (+4*ks)
      bf16x8 af[4], bfv[4];
#pragma unroll
      for (int i = 0; i < 4; ++i) {
        const int mr = mw + i * 16 + li;     // mr&7 == li&7
        af[i] = *(const bf16x8*)(Ab + mr * 64 + ((ck ^ (li & 7)) << 3));
      }
#pragma unroll
      for (int j = 0; j < 4; ++j) {
        const int nr = nw + j * 16 + li;
        bfv[j] = *(const bf16x8*)(Bb + nr * 64 + ((ck ^ (li & 7)) << 3));
      }
#pragma unroll
      for (int i = 0; i < 4; ++i)
#pragma unroll
        for (int j = 0; j < 4; ++j)
          acc[i][j] = __builtin_amdgcn_mfma_f32_16x16x32_bf16(af[i], bfv[j],
                                                              acc[i][j], 0, 0, 0);
    }
  };

  const int nt = K >> 6;   // 8, 16 or 32: always even, >= 2
  stage(0);                // tile 0 -> buf 0
  for (int t = 0; t < nt - 2; t += 2) {
    stage(1);              // tile t+1 -> buf 1
    asm volatile("s_waitcnt vmcnt(8)" ::: "memory");  // tile t landed
    __builtin_amdgcn_s_barrier();
    asm volatile("" ::: "memory");
    compute(std::integral_constant<int, 0>{});
    asm volatile("" ::: "memory");
    __builtin_amdgcn_s_barrier();
    asm volatile("" ::: "memory");
    stage(0);              // tile t+2 -> buf 0
    asm volatile("s_waitcnt vmcnt(8)" ::: "memory");  // tile t+1 landed
    __builtin_amdgcn_s_barrier();
    asm volatile("" ::: "memory");
    compute(std::integral_constant<int, 1>{});
    asm volatile("" ::: "memory");
    __builtin_amdgcn_s_barrier();
    asm volatile("" ::: "memory");
  }
  // tail pair: tiles nt-2 (buf0, already staged) and nt-1 (buf1)
  stage(1);
  asm volatile("s_waitcnt vmcnt(8)" ::: "memory");    // tile nt-2 landed
  __builtin_amdgcn_s_barrier();
  asm volatile("" ::: "memory");
  compute(std::integral_constant<int, 0>{});
  asm volatile("" ::: "memory");
  __builtin_amdgcn_s_barrier();
  asm volatile("" ::: "memory");
  asm volatile("s_waitcnt vmcnt(0)" ::: "memory");    // tile nt-1 landed
  __builtin_amdgcn_s_barrier();
  asm volatile("" ::: "memory");
  compute(std::integral_constant<int, 1>{});

  // epilogue: C/D layout col=lane&15, row=(lane>>4)*4+reg  [m89/m91 verified]
#pragma unroll
  for (int i = 0; i < 4; ++i) {
    const int mrow = m0 + mw + i * 16 + qd * 4;
#pragma unroll
    for (int j = 0; j < 4; ++j) {
      const int ncol = n0 + nw + j * 16 + li;
      const float bv = bias[ncol];
#pragma unroll
      for (int r = 0; r < 4; ++r) {
        const size_t off2 = (size_t)(mrow + r) * N + ncol;
        float v = acc[i][j][r] + bv;
        if (EPI == EPI_BIAS_RES_BF16) v += (float)R[off2];
        out[off2] = (EPI == EPI_BIAS_GELU) ? (bf16)gelu_erf(v) : (bf16)v;
      }
    }
  }
}

// ---------------------------------------------------------------------------
// MFMA attention: one block (4 waves) per (sequence, head).
// P padded to PP (16-mult) for tiles; K-dim of PV padded to PK (32-mult).
// Softmax is group-parallel (G lanes per row, shfl_xor reduce).
// ---------------------------------------------------------------------------
template <int P>
__global__ __launch_bounds__(256) void attn_kernel(const bf16* __restrict__ qkv,
                                                   bf16* __restrict__ out) {
  constexpr int PP   = ((P + 15) / 16) * 16;   // 32, 48, 96
  constexpr int PK   = ((PP + 31) / 32) * 32;  // 32, 64, 96
  constexpr int MT   = PP / 16;
  constexpr int SSTR = PP + 2;                 // fp32 words
  constexpr int VSTR = PK + 8;                 // bf16 elems; *2B is 16B-mult
  constexpr int PSTR = PK + 8;
  constexpr int G    = (P * 8 <= 256) ? 8 : ((P * 4 <= 256) ? 4 : 2);

  __shared__ __align__(16) bf16 QK[2 * PP * 64];  // Q | K ; reused as Ps
  __shared__ __align__(16) bf16 Vt[64 * VSTR];
  __shared__ __align__(16) float Sm[PP * SSTR];
  __shared__ float rsum[PP];

  bf16* Qs = QK;
  bf16* Ks = QK + PP * 64;
  bf16* Ps = QK;  // overlays Q/K after S phase (dead by then)

  const int tid  = threadIdx.x;
  const int lane = tid & 63;
  const int wv   = tid >> 6;
  const int li   = lane & 15;
  const int qd   = lane >> 4;
  const int n    = blockIdx.x >> 3;
  const int h    = blockIdx.x & 7;
  const bf16* base = qkv + (size_t)n * P * QKV_D + h * 64;

  // stage Q,K: 16B chunks, slot = c ^ (r&7)
  for (int t = tid; t < P * 8; t += 256) {
    const int r = t >> 3, c = t & 7;
    const bf16x8 qv = *(const bf16x8*)(base + (size_t)r * QKV_D + c * 8);
    const bf16x8 kv = *(const bf16x8*)(base + (size_t)r * QKV_D + 512 + c * 8);
    *(bf16x8*)(Qs + r * 64 + ((c ^ (r & 7)) * 8)) = qv;
    *(bf16x8*)(Ks + r * 64 + ((c ^ (r & 7)) * 8)) = kv;
  }
  // stage V^T
  for (int t = tid; t < P * 8; t += 256) {
    const int j = t % P, dc = t / P;
    const bf16x8 vv = *(const bf16x8*)(base + (size_t)j * QKV_D + 1024 + dc * 8);
#pragma unroll
    for (int u = 0; u < 8; ++u) Vt[(dc * 8 + u) * VSTR + j] = vv[u];
  }
  if constexpr (PK > P) {
    for (int t = tid; t < 64 * (PK - P); t += 256) {
      const int d = t / (PK - P), j = P + t % (PK - P);
      Vt[d * VSTR + j] = (bf16)0.f;
    }
  }
  __syncthreads();

  // S = Q K^T
  for (int t = wv; t < MT * MT; t += 4) {
    const int ti = t / MT, tj = t % MT;
    f32x4 acc = (f32x4){0.f, 0.f, 0.f, 0.f};
#pragma unroll
    for (int ks = 0; ks < 2; ++ks) {
      const int ck = ks * 4 + qd;
      const int ar = ti * 16 + li;
      const int br = tj * 16 + li;
      const bf16x8 af = *(const bf16x8*)(Qs + ar * 64 + ((ck ^ (ar & 7)) * 8));
      const bf16x8 bv = *(const bf16x8*)(Ks + br * 64 + ((ck ^ (br & 7)) * 8));
      acc = __builtin_amdgcn_mfma_f32_16x16x32_bf16(af, bv, acc, 0, 0, 0);
    }
#pragma unroll
    for (int r = 0; r < 4; ++r)
      Sm[(ti * 16 + qd * 4 + r) * SSTR + tj * 16 + li] = acc[r];
  }
  __syncthreads();

  // softmax: G lanes per row (G|64, groups lane-aligned so shfl_xor stays
  // in-group). unnormalized exp -> bf16 Ps; 1/sum saved for O-write.
  if (tid < P * G) {
    const int row = tid / G, g = tid % G;
    const float* srow = Sm + row * SSTR;
    bf16* prow = Ps + row * PSTR;
    float mx = -1e30f;
    for (int j = g; j < P; j += G) mx = fmaxf(mx, srow[j]);
#pragma unroll
    for (int m = G >> 1; m; m >>= 1) mx = fmaxf(mx, __shfl_xor(mx, m, 64));
    mx *= 0.125f;  // 1/sqrt(64)
    float sum = 0.f;
    for (int j = g; j < P; j += G) {
      const float e = __expf(srow[j] * 0.125f - mx);
      sum += e;
      prow[j] = (bf16)e;
    }
#pragma unroll
    for (int m = G >> 1; m; m >>= 1) sum += __shfl_xor(sum, m, 64);
    for (int j = P + g; j < PK; j += G) prow[j] = (bf16)0.f;
    if (g == 0) rsum[row] = 1.f / sum;
  }
  __syncthreads();

  // O = P V
  for (int t = wv; t < MT * 4; t += 4) {
    const int ti = t >> 2, td = t & 3;
    f32x4 acc = (f32x4){0.f, 0.f, 0.f, 0.f};
#pragma unroll
    for (int ks = 0; ks < PK / 32; ++ks) {
      const int ck = ks * 4 + qd;
      const bf16x8 af = *(const bf16x8*)(Ps + (ti * 16 + li) * PSTR + ck * 8);
      const bf16x8 bv = *(const bf16x8*)(Vt + (td * 16 + li) * VSTR + ck * 8);
      acc = __builtin_amdgcn_mfma_f32_16x16x32_bf16(af, bv, acc, 0, 0, 0);
    }
#pragma unroll
    for (int r = 0; r < 4; ++r) {
      const int row = ti * 16 + qd * 4 + r;
      if (row < P)
        out[(size_t)(n * P + row) * HID + h * 64 + td * 16 + li] =
            (bf16)(acc[r] * rsum[row]);
    }
  }
}

// ---------------------------------------------------------------------------
// LayerNorm over 512, one wave per row. bf16x8 loads/stores. In-place safe
// (each thread reads its own 8 elems, then writes the same 8).
// ---------------------------------------------------------------------------
__global__ __launch_bounds__(256) void ln_kernel(const bf16* __restrict__ Y,
                                                 const float* __restrict__ w,
                                                 const float* __restrict__ b,
                                                 bf16* __restrict__ X) {
  const int row  = blockIdx.x * 4 + (threadIdx.x >> 6);
  const int lane = threadIdx.x & 63;
  const bf16x8 yv = *(const bf16x8*)(Y + (size_t)row * HID + 8 * lane);
  float y[8];
#pragma unroll
  for (int u = 0; u < 8; ++u) y[u] = (float)yv[u];
  float s = 0.f, s2 = 0.f;
#pragma unroll
  for (int u = 0; u < 8; ++u) { s += y[u]; s2 += y[u] * y[u]; }
#pragma unroll
  for (int off = 32; off > 0; off >>= 1) {
    s  += __shfl_xor(s, off, 64);
    s2 += __shfl_xor(s2, off, 64);
  }
  const float mean = s * (1.f / 512.f);
  const float var  = s2 * (1.f / 512.f) - mean * mean;
  const float rstd = rsqrtf(var + 1e-5f);
  const float4 w0 = ((const float4*)w)[2 * lane];
  const float4 w1 = ((const float4*)w)[2 * lane + 1];
  const float4 b0 = ((const float4*)b)[2 * lane];
  const float4 b1 = ((const float4*)b)[2 * lane + 1];
  const float wr[8] = {w0.x, w0.y, w0.z, w0.w, w1.x, w1.y, w1.z, w1.w};
  const float br[8] = {b0.x, b0.y, b0.z, b0.w, b1.x, b1.y, b1.z, b1.w};
  bf16x8 o;
#pragma unroll
  for (int u = 0; u < 8; ++u) o[u] = (bf16)((y[u] - mean) * rstd * wr[u] + br[u]);
  *(bf16x8*)(X + (size_t)row * HID + 8 * lane) = o;
}

// ---------------------------------------------------------------------------
// input projection: h[r,o] = sum_k x[r,k]*w[o,k] + b[o], K=7. Writes the same
// value to nbr consecutive [TOKENS,HID] slices (branches share the input).
// ---------------------------------------------------------------------------
__global__ __launch_bounds__(256) void inproj_kernel(const float* __restrict__ x,
                                                     const float* __restrict__ w,
                                                     const float* __restrict__ b,
                                                     bf16* __restrict__ h,
                                                     int nbr) {
  const int idx = blockIdx.x * 256 + threadIdx.x;
  const int r = idx >> 9, o = idx & 511;
  float s = b[o];
#pragma unroll
  for (int k = 0; k < 7; ++k) s += x[r * 7 + k] * w[o * 7 + k];
  const bf16 bv = (bf16)s;
  for (int q = 0; q < nbr; ++q) h[idx + (size_t)q * TOKENS * HID] = bv;
}

// acc[row] (+)= X[row,:] . w  (per-branch final projection accumulate)
__global__ __launch_bounds__(256) void outdot_kernel(const bf16* __restrict__ X,
                                                     const float* __restrict__ w,
                                                     float* __restrict__ acc,
                                                     int first) {
  const int row  = blockIdx.x * 4 + (threadIdx.x >> 6);
  const int lane = threadIdx.x & 63;
  const bf16* xr = X + (size_t)row * HID;
  const bf16x8 xa = *(const bf16x8*)(xr + 8 * lane);
  const float4 wa = ((const float4*)w)[2 * lane];
  const float4 wb = ((const float4*)w)[2 * lane + 1];
  float s = (float)xa[0] * wa.x + (float)xa[1] * wa.y + (float)xa[2] * wa.z +
            (float)xa[3] * wa.w + (float)xa[4] * wb.x + (float)xa[5] * wb.y +
            (float)xa[6] * wb.z + (float)xa[7] * wb.w;
#pragma unroll
  for (int off = 32; off > 0; off >>= 1) s += __shfl_xor(s, off, 64);
  if (lane == 0) acc[row] = first ? s : (acc[row] + s);
}

// out[b,o] = (1/30) * sum_{j<10} acc[b*960 + o*10 + j] + b_out   (fp32 out)
__global__ __launch_bounds__(256) void pool_kernel(const float* __restrict__ acc,
                                                   const float* __restrict__ ob,
                                                   float* __restrict__ out) {
  const int idx = blockIdx.x * 256 + threadIdx.x;
  if (idx >= 16 * 96) return;
  const int bb = idx / 96, o = idx % 96;
  float s = 0.f;
#pragma unroll
  for (int j = 0; j < 10; ++j) s += acc[bb * 960 + o * 10 + j];
  out[idx] = s * (1.f / 30.f) + ob[0];
}

// ---------------------------------------------------------------------------
extern "C" void kernel_launch(void* const* d_in, const int* in_sizes, int n_in,
                              void* d_out, int out_size, void* d_ws,
                              size_t ws_size, hipStream_t stream) {
  const float* x          = (const float*)d_in[0];
  const float* ip_w       = (const float*)d_in[1];
  const float* ip_b       = (const float*)d_in[2];
  const float* in_proj_w  = (const float*)d_in[3];
  const float* in_proj_b  = (const float*)d_in[4];
  const float* out_proj_w = (const float*)d_in[5];
  const float* out_proj_b = (const float*)d_in[6];
  const float* ffn_w1     = (const float*)d_in[7];
  const float* ffn_b1     = (const float*)d_in[8];
  const float* ffn_w2     = (const float*)d_in[9];
  const float* ffn_b2     = (const float*)d_in[10];
  const float* ln1_w      = (const float*)d_in[11];
  const float* ln1_b      = (const float*)d_in[12];
  const float* ln2_w      = (const float*)d_in[13];
  const float* ln2_b      = (const float*)d_in[14];
  const float* op_w       = (const float*)d_in[15];
  const float* op_b       = (const float*)d_in[16];

  // fixed carve: weights + ACC, then activations (path-dependent)
  char* p = (char*)d_ws;
  bf16* Wq = (bf16*)p; p += (size_t)4 * QKV_D * HID * 2;
  bf16* Wo = (bf16*)p; p += (size_t)4 * HID * HID * 2;
  bf16* W1 = (bf16*)p; p += (size_t)4 * FFN_D * HID * 2;
  bf16* W2 = (bf16*)p; p += (size_t)4 * HID * FFN_D * 2;  // natural layout
  float* ACC = (float*)p; p += (size_t)TOKENS * 4;
  const size_t remain = ws_size - (size_t)(p - (char*)d_ws);

  const size_t T3 = 3 * (size_t)TOKENS;
  // pre-LN buffer eliminated (residual GEMMs write X IN PLACE; LN in place):
  //  batched: X bf16 [T3,512] + BUF bf16 [T3,2048]  ~236 MB
  //           attn phase: QKV [0,1536) | ATT [1536,2048) in BUF
  //           ffn  phase: H = all of BUF (QKV+ATT dead)
  //  seq:     X + BUF over TOKENS rows  ~79 MB
  const size_t need_batched = T3 * HID * 2 + T3 * (size_t)FFN_D * 2;
  const size_t need_seq     = (size_t)TOKENS * HID * 2 + (size_t)TOKENS * FFN_D * 2;
  const bool batched = remain >= need_batched;
  if (!batched && remain < need_seq) return;

  {  // weight conversion fp32 -> bf16 (all natural layouts)
    const int nq = 4 * QKV_D * HID / 4, no = 4 * HID * HID / 4,
              n1 = 4 * FFN_D * HID / 4, n2 = 4 * HID * FFN_D / 4;
    cvt_kernel<<<(nq + 255) / 256, 256, 0, stream>>>(in_proj_w, Wq, nq);
    cvt_kernel<<<(no + 255) / 256, 256, 0, stream>>>(out_proj_w, Wo, no);
    cvt_kernel<<<(n1 + 255) / 256, 256, 0, stream>>>(ffn_w1, W1, n1);
    cvt_kernel<<<(n2 + 255) / 256, 256, 0, stream>>>(ffn_w2, W2, n2);
  }

  static const int periods[3] = {24, 48, 96};
  auto launch_attn = [&](int P, const bf16* q, bf16* o) {
    const int nblk = (TOKENS / P) * 8;
    if (P == 24)      attn_kernel<24><<<nblk, 256, 0, stream>>>(q, o);
    else if (P == 48) attn_kernel<48><<<nblk, 256, 0, stream>>>(q, o);
    else              attn_kernel<96><<<nblk, 256, 0, stream>>>(q, o);
  };

  // one transformer layer on M rows. X updated IN PLACE through the residual
  // chain:
  //   QKV = X @ Wq ; attn -> ATT
  //   X = ATT @ Wo + b + X   (old X dead at the single residual read)
  //   LN1: X -> X
  //   H = gelu(X @ W1 + b1)  (N=2048)
  //   X = H @ W2 + b2 + X    (K=2048; LN1-out dead: FFN1 already consumed it)
  //   LN2: X -> X
  // qkvM: layer-0 batched computes QKV once over TOKENS rows (branches share X).
  auto run_layer = [&](int l, int M, int qkvM, bf16* X, bf16* QKV, bf16* ATT,
                       bf16* H, bool all_br, int br) {
    const int MB = M / 128;
    gemm_bt<EPI_BIAS_BF16><<<dim3(QKV_D / 128, qkvM / 128), 256, 0, stream>>>(
        X, Wq + (size_t)l * QKV_D * HID, in_proj_b + l * QKV_D, nullptr,
        QKV, qkvM, QKV_D, HID);
    if (all_br) {
      for (int b2 = 0; b2 < 3; ++b2) {
        const bf16* q = QKV + (qkvM == M ? (size_t)b2 * TOKENS * QKV_D : 0);
        launch_attn(periods[b2], q, ATT + (size_t)b2 * TOKENS * HID);
      }
    } else {
      launch_attn(periods[br], QKV, ATT);
    }
    gemm_bt<EPI_BIAS_RES_BF16><<<dim3(HID / 128, MB), 256, 0, stream>>>(
        ATT, Wo + (size_t)l * HID * HID, out_proj_b + l * HID, X, X,
        M, HID, HID);
    ln_kernel<<<M / 4, 256, 0, stream>>>(X, ln1_w + l * HID, ln1_b + l * HID, X);
    gemm_bt<EPI_BIAS_GELU><<<dim3(FFN_D / 128, MB), 256, 0, stream>>>(
        X, W1 + (size_t)l * FFN_D * HID, ffn_b1 + l * FFN_D, nullptr,
        H, M, FFN_D, HID);
    gemm_bt<EPI_BIAS_RES_BF16><<<dim3(HID / 128, MB), 256, 0, stream>>>(
        H, W2 + (size_t)l * HID * FFN_D, ffn_b2 + l * HID, X, X,
        M, HID, FFN_D);
    ln_kernel<<<M / 4, 256, 0, stream>>>(X, ln2_w + l * HID, ln2_b + l * HID, X);
  };

  if (batched) {
    bf16* X   = (bf16*)p; p += T3 * HID * 2;
    bf16* BUF = (bf16*)p;
    bf16* QKV = BUF;
    bf16* ATT = BUF + T3 * QKV_D;
    bf16* H   = BUF;               // full T3 x 2048 (QKV+ATT dead by then)
    const int M = (int)T3;

    inproj_kernel<<<TOKENS * HID / 256, 256, 0, stream>>>(x, ip_w, ip_b, X, 3);
    for (int l = 0; l < 4; ++l)
      run_layer(l, M, l == 0 ? TOKENS : M, X, QKV, ATT, H, true, 0);
    for (int br = 0; br < 3; ++br)
      outdot_kernel<<<TOKENS / 4, 256, 0, stream>>>(
          X + (size_t)br * TOKENS * HID, op_w, ACC, br == 0);
  } else {
    // sequential (fits in ~79 MB)
    bf16* X   = (bf16*)p; p += (size_t)TOKENS * HID * 2;
    bf16* BUF = (bf16*)p;
    bf16* QKV = BUF;
    bf16* ATT = BUF + (size_t)TOKENS * QKV_D;
    bf16* H   = BUF;
    const int M = TOKENS;

    for (int br = 0; br < 3; ++br) {
      inproj_kernel<<<TOKENS * HID / 256, 256, 0, stream>>>(x, ip_w, ip_b, X, 1);
      for (int l = 0; l < 4; ++l)
        run_layer(l, M, M, X, QKV, ATT, H, false, br);
      outdot_kernel<<<TOKENS / 4, 256, 0, stream>>>(X, op_w, ACC, br == 0);
    }
  }
  pool_kernel<<<6, 256, 0, stream>>>(ACC, op_b, (float*)d_out);
}